// Round 2
// baseline (218.863 us; speedup 1.0000x reference)
//
#include <hip/hip_runtime.h>
#include <cstdint>
#include <cstddef>

#define N_PIX   16384
#define K_EMB   8192
#define DDIM    256

// ws layout (bytes) — total 23,166,988
#define WS_A8       0           // A fp8 pixel-major [16384][256]    4194304
#define WS_E8       4194304     // E fp8 (x8192) [8192][256]         2097152
#define WS_KEYS     6291456     // keys [128 halves][16384] uint2    16777216
#define WS_ZSQ      23068672    // 16384*4
#define WS_ESQ      23134208    // 8192*4
#define WS_LOSS     23166976    // 8
#define WS_CNT      23166984    // 4

typedef float f32x4 __attribute__((ext_vector_type(4)));

__device__ __forceinline__ unsigned int f32_sortable(float f) {
    unsigned int u = __float_as_uint(f);
    return (u & 0x80000000u) ? ~u : (u | 0x80000000u);
}

// fp32 -> OCP e4m3fn RNE (fallback path; handles subnormals)
__device__ __forceinline__ unsigned char f2fp8(float x) {
    unsigned ub = __float_as_uint(x);
    unsigned sgn = (ub >> 24) & 0x80u;
    unsigned b = ub & 0x7FFFFFFFu;
    unsigned out;
    if (__uint_as_float(b) < 0.015625f) {
        out = (unsigned)(int)rintf(__uint_as_float(b) * 512.0f);
    } else {
        unsigned r = b + 0x7FFFFu + ((b >> 20) & 1u);
        int er = (int)(r >> 23) - 127;
        out = (unsigned)(((er + 7) << 3) | ((r >> 20) & 7u));
    }
    return (unsigned char)(out | sgn);
}

#if defined(__has_builtin)
#if __has_builtin(__builtin_amdgcn_cvt_pk_fp8_f32)
#define HAVE_CVT_FP8 1
#endif
#endif

// pack 4 fp32 -> 4 fp8 bytes (one dword); HW convert when available
__device__ __forceinline__ unsigned pack4_fp8(float a, float b, float c, float d) {
#ifdef HAVE_CVT_FP8
    int pk = 0;
    pk = __builtin_amdgcn_cvt_pk_fp8_f32(a, b, pk, false);  // bytes 0,1
    pk = __builtin_amdgcn_cvt_pk_fp8_f32(c, d, pk, true);   // bytes 2,3
    return (unsigned)pk;
#else
    return (unsigned)f2fp8(a) | ((unsigned)f2fp8(b) << 8)
         | ((unsigned)f2fp8(c) << 16) | ((unsigned)f2fp8(d) << 24);
#endif
}

__device__ __forceinline__ void async16(const unsigned char* g, unsigned char* l) {
    __builtin_amdgcn_global_load_lds(
        (const __attribute__((address_space(1))) void*)g,
        (__attribute__((address_space(3))) void*)l, 16, 0, 0);
}

// np pairwise-sum of squares over 256 contiguous LDS floats (one thread)
__device__ __forceinline__ float np_pairwise_sq256(const float* row) {
    float r[16];
#pragma unroll
    for (int j = 0; j < 16; ++j) r[j] = 0.f;
#pragma unroll
    for (int c = 0; c < 256; ++c) {
        float x  = row[c];
        float sq = __fmul_rn(x, x);
        int slot = ((c >> 7) << 3) | (c & 7);
        r[slot] = __fadd_rn(r[slot], sq);
    }
    float h0 = __fadd_rn(
        __fadd_rn(__fadd_rn(r[0], r[1]), __fadd_rn(r[2], r[3])),
        __fadd_rn(__fadd_rn(r[4], r[5]), __fadd_rn(r[6], r[7])));
    float h1 = __fadd_rn(
        __fadd_rn(__fadd_rn(r[8], r[9]), __fadd_rn(r[10], r[11])),
        __fadd_rn(__fadd_rn(r[12], r[13]), __fadd_rn(r[14], r[15])));
    return __fadd_rn(h0, h1);
}

// ---------------------------------------------------------------- kernel 1
// Fused prep: blocks 0..511 transpose z -> Af8 (fp8) + zsq (np pairwise);
// blocks 512..767 LDS-staged emb -> Ef8 (fp8 of 8192*e) + esq (np pairwise).
__global__ __launch_bounds__(256) void prep_kernel(
        const float* __restrict__ z, const float* __restrict__ emb,
        unsigned char* __restrict__ Af8, unsigned char* __restrict__ Ef8,
        float* __restrict__ zsq, float* __restrict__ esq,
        double* __restrict__ lossAcc, unsigned* __restrict__ doneCnt) {
    __shared__ float tile[32][257];
    int blk = blockIdx.x;
    int t   = threadIdx.x;
    if (blk < 512) {
        int b   = blk >> 5;
        int hw0 = (blk & 31) * 32;
        const float* zb = z + (size_t)b * 262144 + hw0;
        int px = t & 31;
        int cb = t >> 5;
#pragma unroll
        for (int cc = 0; cc < 32; ++cc) {
            int c = cc * 8 + cb;
            tile[px][c] = zb[(size_t)c * 1024 + px];
        }
        __syncthreads();
        int p0 = b * 1024 + hw0;
        int wv = t >> 6, lane = t & 63;
#pragma unroll
        for (int iter = 0; iter < 8; ++iter) {
            int pl = iter * 4 + wv;
            unsigned pk = pack4_fp8(tile[pl][lane * 4 + 0], tile[pl][lane * 4 + 1],
                                    tile[pl][lane * 4 + 2], tile[pl][lane * 4 + 3]);
            ((unsigned*)(Af8 + (size_t)(p0 + pl) * 256))[lane] = pk;
        }
        if (t < 32) zsq[p0 + t] = np_pairwise_sq256(tile[t]);
        if (blk == 0 && t == 0) { *lossAcc = 0.0; *doneCnt = 0u; }
    } else {
        // emb branch: 32 rows per block, coalesced via LDS staging
        int k0 = (blk - 512) * 32;
        const float4* eg = (const float4*)(emb + (size_t)k0 * DDIM);
#pragma unroll
        for (int i = 0; i < 8; ++i) {
            int idx = i * 256 + t;         // 0..2047 float4s
            int row = idx >> 6, c4 = idx & 63;
            float4 v = eg[idx];
            *(float4*)&tile[row][c4 * 4] = v;
        }
        __syncthreads();
#pragma unroll
        for (int i = 0; i < 8; ++i) {
            int idx = i * 256 + t;
            int row = idx >> 6, c4 = idx & 63;
            const float* rp = &tile[row][c4 * 4];
            ((unsigned*)(Ef8 + (size_t)(k0 + row) * 256))[c4] =
                pack4_fp8(rp[0] * 8192.0f, rp[1] * 8192.0f,
                          rp[2] * 8192.0f, rp[3] * 8192.0f);
        }
        if (t < 32) esq[k0 + t] = np_pairwise_sq256(tile[t]);
    }
}

// ---------------------------------------------------------------- kernel 2
// fp8 MFMA GEMM — R1 restructure: K=256 fully LDS-resident (64 KB),
// single staging phase + ONE barrier, then a barrier-free stream of
// 64 ds_read_b64 + 128 MFMAs (was: 16 barriers with vmcnt(0) drains).
// setprio(1) around MFMA clusters (2 independent blocks/CU give the
// scheduler role diversity). ep stride padded 33->35 to spread the
// serial-reduce reads over all 32 banks.
__global__ __launch_bounds__(256) void mfma_score_kernel(
        const unsigned char* __restrict__ Af8,
        const unsigned char* __restrict__ Ef8,
        const float* __restrict__ esq,
        unsigned int* __restrict__ keys) {
    union SM {
        struct { unsigned char As[8][4096]; unsigned char Bs[8][4096]; } k; // 64 KB
        struct { uint2 ep[128][35]; } e;                                    // 35.8 KB
    };
    __shared__ SM sm;
    __shared__ float sEp[128];
    __shared__ uint2 pb[128][2];

    const int nb = blockIdx.x;
    const int mb = blockIdx.y;
    const int t = threadIdx.x;
    const int w = t >> 6, lane = t & 63;
    const int wm = w >> 1, wn = w & 1;
    const int quad = lane >> 4, l16 = lane & 15;

    if (t < 128)
        sEp[t] = (esq[nb * 128 + t] + 0.125f) * 2097152.0f;

    const int rt = t >> 1;
    const int gt = (t & 1) ^ ((t >> 3) & 1);
    const unsigned char* Ag = Af8 + (size_t)(mb * 128 + rt) * 256 + gt * 16;
    const unsigned char* Eg = Ef8 + (size_t)(nb * 128 + rt) * 256 + gt * 16;

    // stage the ENTIRE K=256 (8 chunks of 32B per row), same per-chunk
    // swizzled layout as before: As[ks] == old As[cur] for K-step ks.
#pragma unroll
    for (int ks = 0; ks < 8; ++ks)
        async16(Ag + ks * 32, &sm.k.As[ks][t * 16]);
#pragma unroll
    for (int ks = 0; ks < 8; ++ks)
        async16(Eg + ks * 32, &sm.k.Bs[ks][t * 16]);

    int aaddr[4], baddr[4];
#pragma unroll
    for (int fi = 0; fi < 4; ++fi) {
        int row = wm * 64 + fi * 16 + l16;
        int g   = (quad >> 1) ^ ((row >> 2) & 1);
        aaddr[fi] = row * 32 + g * 16 + (quad & 1) * 8;
    }
#pragma unroll
    for (int fj = 0; fj < 4; ++fj) {
        int row = wn * 64 + fj * 16 + l16;
        int g   = (quad >> 1) ^ ((row >> 2) & 1);
        baddr[fj] = row * 32 + g * 16 + (quad & 1) * 8;
    }

    f32x4 acc[4][4];
#pragma unroll
    for (int i = 0; i < 4; ++i)
#pragma unroll
        for (int j = 0; j < 4; ++j)
#pragma unroll
            for (int r = 0; r < 4; ++r) acc[i][j][r] = 0.f;

    __syncthreads();   // compiler emits vmcnt(0) drain: all 16 stages done

    // barrier-free K sweep: 8 x (8 ds_read_b64 + 16 MFMA)
#pragma unroll
    for (int ks = 0; ks < 8; ++ks) {
        long long af[4], bfr[4];
#pragma unroll
        for (int fi = 0; fi < 4; ++fi)
            af[fi] = *(const long long*)&sm.k.As[ks][aaddr[fi]];
#pragma unroll
        for (int fj = 0; fj < 4; ++fj)
            bfr[fj] = *(const long long*)&sm.k.Bs[ks][baddr[fj]];
        __builtin_amdgcn_s_setprio(1);
#pragma unroll
        for (int fi = 0; fi < 4; ++fi)
#pragma unroll
            for (int fj = 0; fj < 4; ++fj)
                acc[fi][fj] = __builtin_amdgcn_mfma_f32_16x16x32_fp8_fp8(
                    af[fi], bfr[fj], acc[fi][fj], 0, 0, 0);
        __builtin_amdgcn_s_setprio(0);
    }

    __syncthreads();

    float epv[4];
    unsigned idxc[4];
#pragma unroll
    for (int fj = 0; fj < 4; ++fj) {
        int nloc = wn * 64 + fj * 16 + l16;
        epv[fj]  = sEp[nloc];
        idxc[fj] = (unsigned)(nb * 128 + nloc);
    }

#pragma unroll
    for (int fi = 0; fi < 4; ++fi) {
#pragma unroll
        for (int r = 0; r < 4; ++r) {
            unsigned kk[4];
#pragma unroll
            for (int fj = 0; fj < 4; ++fj) {
                unsigned u = (unsigned)fmaf(acc[fi][fj][r], -512.0f, epv[fj]);
                kk[fj] = (u << 13) | idxc[fj];
            }
            unsigned lo0 = min(kk[0], kk[1]), hi0 = max(kk[0], kk[1]);
            unsigned lo1 = min(kk[2], kk[3]), hi1 = max(kk[2], kk[3]);
            unsigned a0 = min(lo0, lo1);
            unsigned a1 = min(max(lo0, lo1), min(hi0, hi1));
            int row = wm * 64 + fi * 16 + quad * 4 + r;
            sm.e.ep[row][wn * 16 + l16] = make_uint2(a0, a1);
        }
    }
    __syncthreads();

    {
        int row = t >> 1, h0 = (t & 1) * 16;
        uint2 mv = sm.e.ep[row][h0];
#pragma unroll
        for (int i = 1; i < 16; ++i) {
            uint2 av = sm.e.ep[row][h0 + i];
            unsigned n0 = min(mv.x, av.x);
            unsigned n1 = min(max(mv.x, av.x), min(mv.y, av.y));
            mv.x = n0; mv.y = n1;
        }
        pb[row][t & 1] = mv;
    }
    __syncthreads();

    {
        int so = t >> 7, row = t & 127;
        ((uint2*)keys)[(size_t)(nb * 2 + so) * N_PIX + (mb * 128 + row)] =
            pb[row][so];
    }
}

// ---------------------------------------------------------------- kernel 3
// Fused final (unchanged): 1024 blocks x 16 pixels, coalesced LDS
// staging of keys, ballot-driven exact rescore, gather + loss + finalize.
__global__ __launch_bounds__(256) void final_kernel(
        const unsigned int* __restrict__ keys,
        const float* __restrict__ z, const float* __restrict__ emb,
        const float* __restrict__ zsq, const float* __restrict__ esq,
        float* __restrict__ out, float* __restrict__ idx_out,
        float* __restrict__ loss_out,
        double* __restrict__ lossAcc, unsigned* __restrict__ doneCnt) {
    __shared__ float ztile[16][260];
    __shared__ uint2 kt[16][129];
    __shared__ int sidx[16];
    int blk = blockIdx.x;                // 0..1023 = b*64 + hh
    int b = blk >> 6, hh = blk & 63;
    int t = threadIdx.x;
    int p0 = b * 1024 + hh * 16;
    const float* zb = z + (size_t)b * 262144 + hh * 16;
    {
        int px = t & 15, cb = t >> 4;
#pragma unroll
        for (int cc = 0; cc < 16; ++cc) {
            int c = cc * 16 + cb;
            ztile[px][c] = zb[(size_t)c * 1024 + px];
        }
    }
    {
        const uint2* kg = (const uint2*)keys;
#pragma unroll
        for (int itr = 0; itr < 8; ++itr) {
            int idx = itr * 256 + t;
            int px = idx & 15, hf = idx >> 4;
            kt[px][hf] = kg[(size_t)hf * N_PIX + p0 + px];
        }
    }
    __syncthreads();

    int wq = t >> 6, lane = t & 63;
#pragma unroll 1
    for (int i = 0; i < 4; ++i) {
        int px = wq * 4 + i;
        int p  = p0 + px;
        uint2 ka = kt[px][lane];
        uint2 kb = kt[px][lane + 64];
        unsigned m = min(min(ka.x, ka.y), min(kb.x, kb.y));
#pragma unroll
        for (int off = 32; off >= 1; off >>= 1)
            m = min(m, (unsigned)__shfl_xor((int)m, off, 64));
        unsigned thr = (m >> 13) + 1600;   // margin 1600*2^-21 = 7.6e-4

        float4 zv = *(const float4*)&ztile[px][lane * 4];
        float zs = zsq[p];
        unsigned long long best = ~0ull;
#pragma unroll 1
        for (int pass = 0; pass < 4; ++pass) {
            unsigned kv = (pass == 0) ? ka.x : (pass == 1) ? ka.y
                        : (pass == 2) ? kb.x : kb.y;
            unsigned long long mm = __ballot((kv >> 13) <= thr);
            while (mm) {
                int src = (int)__builtin_ctzll(mm);
                mm &= mm - 1;
                unsigned keyv = (unsigned)__shfl((int)kv, src, 64);
                int k = (int)(keyv & 0x1FFFu);
                const float4 ev = *(const float4*)(emb + (size_t)k * DDIM + lane * 4);
                double d = (double)zv.x * ev.x + (double)zv.y * ev.y
                         + (double)zv.z * ev.z + (double)zv.w * ev.w;
#pragma unroll
                for (int off = 32; off >= 1; off >>= 1)
                    d += __shfl_down(d, off, 64);
                d = __shfl(d, 0, 64);
                float df = (float)d;
                float s  = __fsub_rn(__fadd_rn(zs, esq[k]), __fmul_rn(2.0f, df));
                unsigned long long key =
                    ((unsigned long long)f32_sortable(s) << 32) | (unsigned)k;
                best = key < best ? key : best;
            }
        }
        if (lane == 0) {
            int k = (int)(unsigned)(best & 0xffffffffu);
            sidx[px] = k;
            idx_out[p] = (float)k;
        }
    }
    __syncthreads();

    int px2 = t & 15, cy = t >> 4;
    int kk = sidx[px2];
    const float* er = emb + (size_t)kk * DDIM;
    float* ob = out + (size_t)b * 262144 + hh * 16;
    float local = 0.f;
#pragma unroll 4
    for (int it = 0; it < 16; ++it) {
        int c = it * 16 + cy;
        float q = er[c];
        float d = q - ztile[px2][c];
        ob[(size_t)c * 1024 + px2] = q;
        local += d * d;
    }
#pragma unroll
    for (int off = 32; off >= 1; off >>= 1) local += __shfl_down(local, off, 64);
    __shared__ float wsum[4];
    if ((t & 63) == 0) wsum[t >> 6] = local;
    __syncthreads();
    if (t == 0) {
        double s = (double)wsum[0] + (double)wsum[1]
                 + (double)wsum[2] + (double)wsum[3];
        atomicAdd(lossAcc, s);
        __threadfence();
        unsigned old = atomicAdd(doneCnt, 1u);
        if (old == 1023u) {
            double tot = atomicAdd(lossAcc, 0.0);
            *loss_out = (float)(tot * (1.25 / 4194304.0));
        }
    }
}

// ----------------------------------------------------------------
extern "C" void kernel_launch(void* const* d_in, const int* in_sizes, int n_in,
                              void* d_out, int out_size, void* d_ws, size_t ws_size,
                              hipStream_t stream) {
    const float* z   = (const float*)d_in[0];
    const float* emb = (const float*)d_in[1];
    float* out = (float*)d_out;
    char* ws = (char*)d_ws;

    unsigned char* Af8 = (unsigned char*)(ws + WS_A8);
    unsigned char* Ef8 = (unsigned char*)(ws + WS_E8);
    unsigned int* keys = (unsigned int*)(ws + WS_KEYS);
    float* zsq      = (float*)(ws + WS_ZSQ);
    float* esq      = (float*)(ws + WS_ESQ);
    double* lossAcc = (double*)(ws + WS_LOSS);
    unsigned* doneCnt = (unsigned*)(ws + WS_CNT);

    prep_kernel<<<768, 256, 0, stream>>>(z, emb, Af8, Ef8, zsq, esq,
                                         lossAcc, doneCnt);
    mfma_score_kernel<<<dim3(64, 128), 256, 0, stream>>>(Af8, Ef8, esq, keys);
    final_kernel<<<1024, 256, 0, stream>>>(keys, z, emb, zsq, esq,
                                           out, out + 4194305, out + 4194304,
                                           lossAcc, doneCnt);
}

// Round 3
// 213.865 us; speedup vs baseline: 1.0234x; 1.0234x over previous
//
#include <hip/hip_runtime.h>
#include <cstdint>
#include <cstddef>

#define N_PIX   16384
#define K_EMB   8192
#define DDIM    256

// ws layout (bytes) — total 23,166,988
// Af8/Ef8 are now CHUNK-MAJOR: [blk128][ks=8][4096B], where within a 4096B
// chunk, byte t*16+j holds row (t>>1), k-byte ks*32 + gt*16 + j,
// gt = (t&1)^((t>>3)&1)  — exactly the score kernel's LDS image.
#define WS_A8       0           // A fp8 chunk-major [128][8][4096]   4194304
#define WS_E8       4194304     // E fp8 (x8192) [64][8][4096]        2097152
#define WS_KEYS     6291456     // keys [128 halves][16384] uint2    16777216
#define WS_ZSQ      23068672    // 16384*4
#define WS_ESQ      23134208    // 8192*4
#define WS_LOSS     23166976    // 8
#define WS_CNT      23166984    // 4

typedef float f32x4 __attribute__((ext_vector_type(4)));

__device__ __forceinline__ unsigned int f32_sortable(float f) {
    unsigned int u = __float_as_uint(f);
    return (u & 0x80000000u) ? ~u : (u | 0x80000000u);
}

// fp32 -> OCP e4m3fn RNE (fallback path; handles subnormals)
__device__ __forceinline__ unsigned char f2fp8(float x) {
    unsigned ub = __float_as_uint(x);
    unsigned sgn = (ub >> 24) & 0x80u;
    unsigned b = ub & 0x7FFFFFFFu;
    unsigned out;
    if (__uint_as_float(b) < 0.015625f) {
        out = (unsigned)(int)rintf(__uint_as_float(b) * 512.0f);
    } else {
        unsigned r = b + 0x7FFFFu + ((b >> 20) & 1u);
        int er = (int)(r >> 23) - 127;
        out = (unsigned)(((er + 7) << 3) | ((r >> 20) & 7u));
    }
    return (unsigned char)(out | sgn);
}

#if defined(__has_builtin)
#if __has_builtin(__builtin_amdgcn_cvt_pk_fp8_f32)
#define HAVE_CVT_FP8 1
#endif
#endif

// pack 4 fp32 -> 4 fp8 bytes (one dword); HW convert when available
__device__ __forceinline__ unsigned pack4_fp8(float a, float b, float c, float d) {
#ifdef HAVE_CVT_FP8
    int pk = 0;
    pk = __builtin_amdgcn_cvt_pk_fp8_f32(a, b, pk, false);  // bytes 0,1
    pk = __builtin_amdgcn_cvt_pk_fp8_f32(c, d, pk, true);   // bytes 2,3
    return (unsigned)pk;
#else
    return (unsigned)f2fp8(a) | ((unsigned)f2fp8(b) << 8)
         | ((unsigned)f2fp8(c) << 16) | ((unsigned)f2fp8(d) << 24);
#endif
}

__device__ __forceinline__ void async16(const unsigned char* g, unsigned char* l) {
    __builtin_amdgcn_global_load_lds(
        (const __attribute__((address_space(1))) void*)g,
        (__attribute__((address_space(3))) void*)l, 16, 0, 0);
}

// np pairwise-sum of squares over 256 contiguous LDS floats (one thread)
__device__ __forceinline__ float np_pairwise_sq256(const float* row) {
    float r[16];
#pragma unroll
    for (int j = 0; j < 16; ++j) r[j] = 0.f;
#pragma unroll
    for (int c = 0; c < 256; ++c) {
        float x  = row[c];
        float sq = __fmul_rn(x, x);
        int slot = ((c >> 7) << 3) | (c & 7);
        r[slot] = __fadd_rn(r[slot], sq);
    }
    float h0 = __fadd_rn(
        __fadd_rn(__fadd_rn(r[0], r[1]), __fadd_rn(r[2], r[3])),
        __fadd_rn(__fadd_rn(r[4], r[5]), __fadd_rn(r[6], r[7])));
    float h1 = __fadd_rn(
        __fadd_rn(__fadd_rn(r[8], r[9]), __fadd_rn(r[10], r[11])),
        __fadd_rn(__fadd_rn(r[12], r[13]), __fadd_rn(r[14], r[15])));
    return __fadd_rn(h0, h1);
}

// chunk-major byte offset for (row-in-128 r, byte-column c) within one
// 32 KB block: ks = c>>5, h = (c>>4)&1, s = h ^ ((r>>2)&1)
__device__ __forceinline__ size_t cm_addr(int r, int c) {
    int ks = c >> 5;
    int h  = (c >> 4) & 1;
    int s  = h ^ ((r >> 2) & 1);
    return (size_t)ks * 4096 + (size_t)r * 32 + s * 16 + (c & 15);
}

// ---------------------------------------------------------------- kernel 1
// Fused prep: blocks 0..511 transpose z -> Af8 (fp8, chunk-major) + zsq;
// blocks 512..767 LDS-staged emb -> Ef8 (fp8 of 8192*e, chunk-major) + esq.
__global__ __launch_bounds__(256) void prep_kernel(
        const float* __restrict__ z, const float* __restrict__ emb,
        unsigned char* __restrict__ Af8, unsigned char* __restrict__ Ef8,
        float* __restrict__ zsq, float* __restrict__ esq,
        double* __restrict__ lossAcc, unsigned* __restrict__ doneCnt) {
    __shared__ float tile[32][257];
    int blk = blockIdx.x;
    int t   = threadIdx.x;
    if (blk < 512) {
        int b   = blk >> 5;
        int hw0 = (blk & 31) * 32;
        const float* zb = z + (size_t)b * 262144 + hw0;
        int px = t & 31;
        int cb = t >> 5;
#pragma unroll
        for (int cc = 0; cc < 32; ++cc) {
            int c = cc * 8 + cb;
            tile[px][c] = zb[(size_t)c * 1024 + px];
        }
        __syncthreads();
        int p0 = b * 1024 + hw0;
        int wv = t >> 6, lane = t & 63;
#pragma unroll
        for (int iter = 0; iter < 8; ++iter) {
            int pl = iter * 4 + wv;
            unsigned pk = pack4_fp8(tile[pl][lane * 4 + 0], tile[pl][lane * 4 + 1],
                                    tile[pl][lane * 4 + 2], tile[pl][lane * 4 + 3]);
            int p  = p0 + pl;
            int mb = p >> 7, r = p & 127;
            *(unsigned*)(Af8 + (size_t)mb * 32768 + cm_addr(r, lane * 4)) = pk;
        }
        if (t < 32) zsq[p0 + t] = np_pairwise_sq256(tile[t]);
        if (blk == 0 && t == 0) { *lossAcc = 0.0; *doneCnt = 0u; }
    } else {
        // emb branch: 32 rows per block, coalesced via LDS staging
        int k0 = (blk - 512) * 32;
        const float4* eg = (const float4*)(emb + (size_t)k0 * DDIM);
#pragma unroll
        for (int i = 0; i < 8; ++i) {
            int idx = i * 256 + t;         // 0..2047 float4s
            int row = idx >> 6, c4 = idx & 63;
            float4 v = eg[idx];
            *(float4*)&tile[row][c4 * 4] = v;
        }
        __syncthreads();
#pragma unroll
        for (int i = 0; i < 8; ++i) {
            int idx = i * 256 + t;
            int row = idx >> 6, c4 = idx & 63;
            const float* rp = &tile[row][c4 * 4];
            int kg = k0 + row;
            int nb = kg >> 7, rr = kg & 127;
            *(unsigned*)(Ef8 + (size_t)nb * 32768 + cm_addr(rr, c4 * 4)) =
                pack4_fp8(rp[0] * 8192.0f, rp[1] * 8192.0f,
                          rp[2] * 8192.0f, rp[3] * 8192.0f);
        }
        if (t < 32) esq[k0 + t] = np_pairwise_sq256(tile[t]);
    }
}

// ---------------------------------------------------------------- kernel 2
// fp8 MFMA GEMM — R2: staging now reads CHUNK-MAJOR Af8/Ef8 so every
// global_load_lds is 1 KB fully contiguous (was 32 scattered 32B rows).
// LDS image and all fragment addressing identical to R0/R1.
__global__ __launch_bounds__(256) void mfma_score_kernel(
        const unsigned char* __restrict__ Af8,
        const unsigned char* __restrict__ Ef8,
        const float* __restrict__ esq,
        unsigned int* __restrict__ keys) {
    union SM {
        struct { unsigned char As[8][4096]; unsigned char Bs[8][4096]; } k; // 64 KB
        struct { uint2 ep[128][35]; } e;                                    // 35.8 KB
    };
    __shared__ SM sm;
    __shared__ float sEp[128];
    __shared__ uint2 pb[128][2];

    const int nb = blockIdx.x;
    const int mb = blockIdx.y;
    const int t = threadIdx.x;
    const int w = t >> 6, lane = t & 63;
    const int wm = w >> 1, wn = w & 1;
    const int quad = lane >> 4, l16 = lane & 15;

    if (t < 128)
        sEp[t] = (esq[nb * 128 + t] + 0.125f) * 2097152.0f;

    // contiguous chunk-major staging: per instruction, the wave loads
    // 1 KB linearly; the 4 waves tile each 4 KB chunk.
    const unsigned char* Ag = Af8 + (size_t)mb * 32768 + t * 16;
    const unsigned char* Eg = Ef8 + (size_t)nb * 32768 + t * 16;
#pragma unroll
    for (int ks = 0; ks < 8; ++ks)
        async16(Ag + ks * 4096, &sm.k.As[ks][t * 16]);
#pragma unroll
    for (int ks = 0; ks < 8; ++ks)
        async16(Eg + ks * 4096, &sm.k.Bs[ks][t * 16]);

    int aaddr[4], baddr[4];
#pragma unroll
    for (int fi = 0; fi < 4; ++fi) {
        int row = wm * 64 + fi * 16 + l16;
        int g   = (quad >> 1) ^ ((row >> 2) & 1);
        aaddr[fi] = row * 32 + g * 16 + (quad & 1) * 8;
    }
#pragma unroll
    for (int fj = 0; fj < 4; ++fj) {
        int row = wn * 64 + fj * 16 + l16;
        int g   = (quad >> 1) ^ ((row >> 2) & 1);
        baddr[fj] = row * 32 + g * 16 + (quad & 1) * 8;
    }

    f32x4 acc[4][4];
#pragma unroll
    for (int i = 0; i < 4; ++i)
#pragma unroll
        for (int j = 0; j < 4; ++j)
#pragma unroll
            for (int r = 0; r < 4; ++r) acc[i][j][r] = 0.f;

    __syncthreads();   // vmcnt(0) drain: all 16 staged KB present

    // barrier-free K sweep: 8 x (8 ds_read_b64 + 16 MFMA)
#pragma unroll
    for (int ks = 0; ks < 8; ++ks) {
        long long af[4], bfr[4];
#pragma unroll
        for (int fi = 0; fi < 4; ++fi)
            af[fi] = *(const long long*)&sm.k.As[ks][aaddr[fi]];
#pragma unroll
        for (int fj = 0; fj < 4; ++fj)
            bfr[fj] = *(const long long*)&sm.k.Bs[ks][baddr[fj]];
        __builtin_amdgcn_s_setprio(1);
#pragma unroll
        for (int fi = 0; fi < 4; ++fi)
#pragma unroll
            for (int fj = 0; fj < 4; ++fj)
                acc[fi][fj] = __builtin_amdgcn_mfma_f32_16x16x32_fp8_fp8(
                    af[fi], bfr[fj], acc[fi][fj], 0, 0, 0);
        __builtin_amdgcn_s_setprio(0);
    }

    __syncthreads();

    float epv[4];
    unsigned idxc[4];
#pragma unroll
    for (int fj = 0; fj < 4; ++fj) {
        int nloc = wn * 64 + fj * 16 + l16;
        epv[fj]  = sEp[nloc];
        idxc[fj] = (unsigned)(nb * 128 + nloc);
    }

#pragma unroll
    for (int fi = 0; fi < 4; ++fi) {
#pragma unroll
        for (int r = 0; r < 4; ++r) {
            unsigned kk[4];
#pragma unroll
            for (int fj = 0; fj < 4; ++fj) {
                unsigned u = (unsigned)fmaf(acc[fi][fj][r], -512.0f, epv[fj]);
                kk[fj] = (u << 13) | idxc[fj];
            }
            unsigned lo0 = min(kk[0], kk[1]), hi0 = max(kk[0], kk[1]);
            unsigned lo1 = min(kk[2], kk[3]), hi1 = max(kk[2], kk[3]);
            unsigned a0 = min(lo0, lo1);
            unsigned a1 = min(max(lo0, lo1), min(hi0, hi1));
            int row = wm * 64 + fi * 16 + quad * 4 + r;
            sm.e.ep[row][wn * 16 + l16] = make_uint2(a0, a1);
        }
    }
    __syncthreads();

    {
        int row = t >> 1, h0 = (t & 1) * 16;
        uint2 mv = sm.e.ep[row][h0];
#pragma unroll
        for (int i = 1; i < 16; ++i) {
            uint2 av = sm.e.ep[row][h0 + i];
            unsigned n0 = min(mv.x, av.x);
            unsigned n1 = min(max(mv.x, av.x), min(mv.y, av.y));
            mv.x = n0; mv.y = n1;
        }
        pb[row][t & 1] = mv;
    }
    __syncthreads();

    {
        int so = t >> 7, row = t & 127;
        ((uint2*)keys)[(size_t)(nb * 2 + so) * N_PIX + (mb * 128 + row)] =
            pb[row][so];
    }
}

// ---------------------------------------------------------------- kernel 3
// Fused final (unchanged): 1024 blocks x 16 pixels, coalesced LDS
// staging of keys, ballot-driven exact rescore, gather + loss + finalize.
__global__ __launch_bounds__(256) void final_kernel(
        const unsigned int* __restrict__ keys,
        const float* __restrict__ z, const float* __restrict__ emb,
        const float* __restrict__ zsq, const float* __restrict__ esq,
        float* __restrict__ out, float* __restrict__ idx_out,
        float* __restrict__ loss_out,
        double* __restrict__ lossAcc, unsigned* __restrict__ doneCnt) {
    __shared__ float ztile[16][260];
    __shared__ uint2 kt[16][129];
    __shared__ int sidx[16];
    int blk = blockIdx.x;                // 0..1023 = b*64 + hh
    int b = blk >> 6, hh = blk & 63;
    int t = threadIdx.x;
    int p0 = b * 1024 + hh * 16;
    const float* zb = z + (size_t)b * 262144 + hh * 16;
    {
        int px = t & 15, cb = t >> 4;
#pragma unroll
        for (int cc = 0; cc < 16; ++cc) {
            int c = cc * 16 + cb;
            ztile[px][c] = zb[(size_t)c * 1024 + px];
        }
    }
    {
        const uint2* kg = (const uint2*)keys;
#pragma unroll
        for (int itr = 0; itr < 8; ++itr) {
            int idx = itr * 256 + t;
            int px = idx & 15, hf = idx >> 4;
            kt[px][hf] = kg[(size_t)hf * N_PIX + p0 + px];
        }
    }
    __syncthreads();

    int wq = t >> 6, lane = t & 63;
#pragma unroll 1
    for (int i = 0; i < 4; ++i) {
        int px = wq * 4 + i;
        int p  = p0 + px;
        uint2 ka = kt[px][lane];
        uint2 kb = kt[px][lane + 64];
        unsigned m = min(min(ka.x, ka.y), min(kb.x, kb.y));
#pragma unroll
        for (int off = 32; off >= 1; off >>= 1)
            m = min(m, (unsigned)__shfl_xor((int)m, off, 64));
        unsigned thr = (m >> 13) + 1600;   // margin 1600*2^-21 = 7.6e-4

        float4 zv = *(const float4*)&ztile[px][lane * 4];
        float zs = zsq[p];
        unsigned long long best = ~0ull;
#pragma unroll 1
        for (int pass = 0; pass < 4; ++pass) {
            unsigned kv = (pass == 0) ? ka.x : (pass == 1) ? ka.y
                        : (pass == 2) ? kb.x : kb.y;
            unsigned long long mm = __ballot((kv >> 13) <= thr);
            while (mm) {
                int src = (int)__builtin_ctzll(mm);
                mm &= mm - 1;
                unsigned keyv = (unsigned)__shfl((int)kv, src, 64);
                int k = (int)(keyv & 0x1FFFu);
                const float4 ev = *(const float4*)(emb + (size_t)k * DDIM + lane * 4);
                double d = (double)zv.x * ev.x + (double)zv.y * ev.y
                         + (double)zv.z * ev.z + (double)zv.w * ev.w;
#pragma unroll
                for (int off = 32; off >= 1; off >>= 1)
                    d += __shfl_down(d, off, 64);
                d = __shfl(d, 0, 64);
                float df = (float)d;
                float s  = __fsub_rn(__fadd_rn(zs, esq[k]), __fmul_rn(2.0f, df));
                unsigned long long key =
                    ((unsigned long long)f32_sortable(s) << 32) | (unsigned)k;
                best = key < best ? key : best;
            }
        }
        if (lane == 0) {
            int k = (int)(unsigned)(best & 0xffffffffu);
            sidx[px] = k;
            idx_out[p] = (float)k;
        }
    }
    __syncthreads();

    int px2 = t & 15, cy = t >> 4;
    int kk = sidx[px2];
    const float* er = emb + (size_t)kk * DDIM;
    float* ob = out + (size_t)b * 262144 + hh * 16;
    float local = 0.f;
#pragma unroll 4
    for (int it = 0; it < 16; ++it) {
        int c = it * 16 + cy;
        float q = er[c];
        float d = q - ztile[px2][c];
        ob[(size_t)c * 1024 + px2] = q;
        local += d * d;
    }
#pragma unroll
    for (int off = 32; off >= 1; off >>= 1) local += __shfl_down(local, off, 64);
    __shared__ float wsum[4];
    if ((t & 63) == 0) wsum[t >> 6] = local;
    __syncthreads();
    if (t == 0) {
        double s = (double)wsum[0] + (double)wsum[1]
                 + (double)wsum[2] + (double)wsum[3];
        atomicAdd(lossAcc, s);
        __threadfence();
        unsigned old = atomicAdd(doneCnt, 1u);
        if (old == 1023u) {
            double tot = atomicAdd(lossAcc, 0.0);
            *loss_out = (float)(tot * (1.25 / 4194304.0));
        }
    }
}

// ----------------------------------------------------------------
extern "C" void kernel_launch(void* const* d_in, const int* in_sizes, int n_in,
                              void* d_out, int out_size, void* d_ws, size_t ws_size,
                              hipStream_t stream) {
    const float* z   = (const float*)d_in[0];
    const float* emb = (const float*)d_in[1];
    float* out = (float*)d_out;
    char* ws = (char*)d_ws;

    unsigned char* Af8 = (unsigned char*)(ws + WS_A8);
    unsigned char* Ef8 = (unsigned char*)(ws + WS_E8);
    unsigned int* keys = (unsigned int*)(ws + WS_KEYS);
    float* zsq      = (float*)(ws + WS_ZSQ);
    float* esq      = (float*)(ws + WS_ESQ);
    double* lossAcc = (double*)(ws + WS_LOSS);
    unsigned* doneCnt = (unsigned*)(ws + WS_CNT);

    prep_kernel<<<768, 256, 0, stream>>>(z, emb, Af8, Ef8, zsq, esq,
                                         lossAcc, doneCnt);
    mfma_score_kernel<<<dim3(64, 128), 256, 0, stream>>>(Af8, Ef8, esq, keys);
    final_kernel<<<1024, 256, 0, stream>>>(keys, z, emb, zsq, esq,
                                           out, out + 4194305, out + 4194304,
                                           lossAcc, doneCnt);
}

// Round 4
// 197.851 us; speedup vs baseline: 1.1062x; 1.0809x over previous
//
#include <hip/hip_runtime.h>
#include <cstdint>
#include <cstddef>

#define N_PIX   16384
#define K_EMB   8192
#define DDIM    256

// ws layout (bytes) — unchanged offsets; keys region now only 4MB used
#define WS_A8       0           // A fp8 chunk-major [128][8][4096]   4194304
#define WS_E8       4194304     // E fp8 (x8192) [64][8][4096]        2097152
#define WS_KEYS     6291456     // keys [32 subs][16384] uint2        4194304
#define WS_ZSQ      23068672    // 16384*4
#define WS_ESQ      23134208    // 8192*4
#define WS_LOSS     23166976    // 8
#define WS_CNT      23166984    // 4

typedef float f32x4 __attribute__((ext_vector_type(4)));

__device__ __forceinline__ unsigned int f32_sortable(float f) {
    unsigned int u = __float_as_uint(f);
    return (u & 0x80000000u) ? ~u : (u | 0x80000000u);
}

// fp32 -> OCP e4m3fn RNE (fallback path; handles subnormals)
__device__ __forceinline__ unsigned char f2fp8(float x) {
    unsigned ub = __float_as_uint(x);
    unsigned sgn = (ub >> 24) & 0x80u;
    unsigned b = ub & 0x7FFFFFFFu;
    unsigned out;
    if (__uint_as_float(b) < 0.015625f) {
        out = (unsigned)(int)rintf(__uint_as_float(b) * 512.0f);
    } else {
        unsigned r = b + 0x7FFFFu + ((b >> 20) & 1u);
        int er = (int)(r >> 23) - 127;
        out = (unsigned)(((er + 7) << 3) | ((r >> 20) & 7u));
    }
    return (unsigned char)(out | sgn);
}

#if defined(__has_builtin)
#if __has_builtin(__builtin_amdgcn_cvt_pk_fp8_f32)
#define HAVE_CVT_FP8 1
#endif
#endif

__device__ __forceinline__ unsigned pack4_fp8(float a, float b, float c, float d) {
#ifdef HAVE_CVT_FP8
    int pk = 0;
    pk = __builtin_amdgcn_cvt_pk_fp8_f32(a, b, pk, false);
    pk = __builtin_amdgcn_cvt_pk_fp8_f32(c, d, pk, true);
    return (unsigned)pk;
#else
    return (unsigned)f2fp8(a) | ((unsigned)f2fp8(b) << 8)
         | ((unsigned)f2fp8(c) << 16) | ((unsigned)f2fp8(d) << 24);
#endif
}

__device__ __forceinline__ void async16(const unsigned char* g, unsigned char* l) {
    __builtin_amdgcn_global_load_lds(
        (const __attribute__((address_space(1))) void*)g,
        (__attribute__((address_space(3))) void*)l, 16, 0, 0);
}

// np pairwise-sum of squares over 256 contiguous LDS floats (one thread)
__device__ __forceinline__ float np_pairwise_sq256(const float* row) {
    float r[16];
#pragma unroll
    for (int j = 0; j < 16; ++j) r[j] = 0.f;
#pragma unroll
    for (int c = 0; c < 256; ++c) {
        float x  = row[c];
        float sq = __fmul_rn(x, x);
        int slot = ((c >> 7) << 3) | (c & 7);
        r[slot] = __fadd_rn(r[slot], sq);
    }
    float h0 = __fadd_rn(
        __fadd_rn(__fadd_rn(r[0], r[1]), __fadd_rn(r[2], r[3])),
        __fadd_rn(__fadd_rn(r[4], r[5]), __fadd_rn(r[6], r[7])));
    float h1 = __fadd_rn(
        __fadd_rn(__fadd_rn(r[8], r[9]), __fadd_rn(r[10], r[11])),
        __fadd_rn(__fadd_rn(r[12], r[13]), __fadd_rn(r[14], r[15])));
    return __fadd_rn(h0, h1);
}

// chunk-major byte offset for (row-in-128 r, byte-column c) within one
// 32 KB block: ks = c>>5, h = (c>>4)&1, s = h ^ ((r>>2)&1)
__device__ __forceinline__ size_t cm_addr(int r, int c) {
    int ks = c >> 5;
    int h  = (c >> 4) & 1;
    int s  = h ^ ((r >> 2) & 1);
    return (size_t)ks * 4096 + (size_t)r * 32 + s * 16 + (c & 15);
}

// ---------------------------------------------------------------- kernel 1
// unchanged from R2 (chunk-major Af8/Ef8 writers)
__global__ __launch_bounds__(256) void prep_kernel(
        const float* __restrict__ z, const float* __restrict__ emb,
        unsigned char* __restrict__ Af8, unsigned char* __restrict__ Ef8,
        float* __restrict__ zsq, float* __restrict__ esq,
        double* __restrict__ lossAcc, unsigned* __restrict__ doneCnt) {
    __shared__ float tile[32][257];
    int blk = blockIdx.x;
    int t   = threadIdx.x;
    if (blk < 512) {
        int b   = blk >> 5;
        int hw0 = (blk & 31) * 32;
        const float* zb = z + (size_t)b * 262144 + hw0;
        int px = t & 31;
        int cb = t >> 5;
#pragma unroll
        for (int cc = 0; cc < 32; ++cc) {
            int c = cc * 8 + cb;
            tile[px][c] = zb[(size_t)c * 1024 + px];
        }
        __syncthreads();
        int p0 = b * 1024 + hw0;
        int wv = t >> 6, lane = t & 63;
#pragma unroll
        for (int iter = 0; iter < 8; ++iter) {
            int pl = iter * 4 + wv;
            unsigned pk = pack4_fp8(tile[pl][lane * 4 + 0], tile[pl][lane * 4 + 1],
                                    tile[pl][lane * 4 + 2], tile[pl][lane * 4 + 3]);
            int p  = p0 + pl;
            int mb = p >> 7, r = p & 127;
            *(unsigned*)(Af8 + (size_t)mb * 32768 + cm_addr(r, lane * 4)) = pk;
        }
        if (t < 32) zsq[p0 + t] = np_pairwise_sq256(tile[t]);
        if (blk == 0 && t == 0) { *lossAcc = 0.0; *doneCnt = 0u; }
    } else {
        int k0 = (blk - 512) * 32;
        const float4* eg = (const float4*)(emb + (size_t)k0 * DDIM);
#pragma unroll
        for (int i = 0; i < 8; ++i) {
            int idx = i * 256 + t;
            int row = idx >> 6, c4 = idx & 63;
            float4 v = eg[idx];
            *(float4*)&tile[row][c4 * 4] = v;
        }
        __syncthreads();
#pragma unroll
        for (int i = 0; i < 8; ++i) {
            int idx = i * 256 + t;
            int row = idx >> 6, c4 = idx & 63;
            const float* rp = &tile[row][c4 * 4];
            int kg = k0 + row;
            int nb = kg >> 7, rr = kg & 127;
            *(unsigned*)(Ef8 + (size_t)nb * 32768 + cm_addr(rr, c4 * 4)) =
                pack4_fp8(rp[0] * 8192.0f, rp[1] * 8192.0f,
                          rp[2] * 8192.0f, rp[3] * 8192.0f);
        }
        if (t < 32) esq[k0 + t] = np_pairwise_sq256(tile[t]);
    }
}

// winner float (idx in low 13 mantissa bits) -> integer key
// u = trunc(262144 - 512*w), clamped to 19 bits; key = (u<<13)|idx
__device__ __forceinline__ unsigned pack_key(float w) {
    float uf = __builtin_fmaf(w, -512.0f, 262144.0f);
    uf = fminf(uf, 524287.0f);
    unsigned u = (unsigned)uf;
    return (u << 13) | (__float_as_uint(w) & 0x1FFFu);
}

// ---------------------------------------------------------------- kernel 2
// R3: nb-sweep. grid (16 groups x 128 mb). A-tile register-resident
// (loaded once via LDS), sweep 4 E-tiles; per-element selection in
// FLOAT domain with idx packed in mantissa LSBs (1 and_or + 3 min/max
// per element); integer keys built only for the 32 winners per thread.
// keys = top-2 per (g, wn) sub-group of 256 embeddings: [32][16384] uint2.
__global__ __launch_bounds__(256) void mfma_score_kernel(
        const unsigned char* __restrict__ Af8,
        const unsigned char* __restrict__ Ef8,
        unsigned int* __restrict__ keys) {
    union SM {
        struct { unsigned char As[8][4096]; unsigned char Bs[8][4096]; } k; // 64 KB
        struct { uint2 ep[128][33]; } e;   // 33.8 KB, reused post-compute
    };
    __shared__ SM sm;

    const int g  = blockIdx.x;      // 0..15: embedding group of 4 nb-tiles
    const int mb = blockIdx.y;      // 0..127: pixel tile
    const int t = threadIdx.x;
    const int w = t >> 6, lane = t & 63;
    const int wm = w >> 1, wn = w & 1;
    const int quad = lane >> 4, l16 = lane & 15;

    // stage A (once) and first E tile
    const unsigned char* Ag = Af8 + (size_t)mb * 32768 + t * 16;
#pragma unroll
    for (int ks = 0; ks < 8; ++ks)
        async16(Ag + ks * 4096, &sm.k.As[ks][t * 16]);
    {
        const unsigned char* Eg = Ef8 + (size_t)(g * 4) * 32768 + t * 16;
#pragma unroll
        for (int ks = 0; ks < 8; ++ks)
            async16(Eg + ks * 4096, &sm.k.Bs[ks][t * 16]);
    }

    int aaddr[4], baddr[4];
#pragma unroll
    for (int fi = 0; fi < 4; ++fi) {
        int row = wm * 64 + fi * 16 + l16;
        int gg  = (quad >> 1) ^ ((row >> 2) & 1);
        aaddr[fi] = row * 32 + gg * 16 + (quad & 1) * 8;
    }
#pragma unroll
    for (int fj = 0; fj < 4; ++fj) {
        int row = wn * 64 + fj * 16 + l16;
        int gg  = (quad >> 1) ^ ((row >> 2) & 1);
        baddr[fj] = row * 32 + gg * 16 + (quad & 1) * 8;
    }

    __syncthreads();   // A + E0 staged

    // A-fragments to registers (reused across the 4-tile sweep)
    long long afr[4][8];
#pragma unroll
    for (int fi = 0; fi < 4; ++fi)
#pragma unroll
        for (int ks = 0; ks < 8; ++ks)
            afr[fi][ks] = *(const long long*)&sm.k.As[ks][aaddr[fi]];

    const float NEGINF = __int_as_float(0xFF800000);
    float t2a[16], t2b[16];
#pragma unroll
    for (int i = 0; i < 16; ++i) { t2a[i] = NEGINF; t2b[i] = NEGINF; }

#pragma unroll 1
    for (int j = 0; j < 4; ++j) {
        f32x4 acc[4][4];
#pragma unroll
        for (int i = 0; i < 4; ++i)
#pragma unroll
            for (int jj = 0; jj < 4; ++jj)
#pragma unroll
                for (int r = 0; r < 4; ++r) acc[i][jj][r] = 0.f;

#pragma unroll
        for (int ks = 0; ks < 8; ++ks) {
            long long bfr[4];
#pragma unroll
            for (int fj = 0; fj < 4; ++fj)
                bfr[fj] = *(const long long*)&sm.k.Bs[ks][baddr[fj]];
            __builtin_amdgcn_s_setprio(1);
#pragma unroll
            for (int fi = 0; fi < 4; ++fi)
#pragma unroll
                for (int fj = 0; fj < 4; ++fj)
                    acc[fi][fj] = __builtin_amdgcn_mfma_f32_16x16x32_fp8_fp8(
                        afr[fi][ks], bfr[fj], acc[fi][fj], 0, 0, 0);
            __builtin_amdgcn_s_setprio(0);
        }
        __syncthreads();   // all waves done reading Bs

        if (j < 3) {
            const unsigned char* Eg =
                Ef8 + (size_t)(g * 4 + j + 1) * 32768 + t * 16;
#pragma unroll
            for (int ks = 0; ks < 8; ++ks)
                async16(Eg + ks * 4096, &sm.k.Bs[ks][t * 16]);
        }

        // selection (pure VALU, overlaps the staging above)
        const int nb = g * 4 + j;
        const unsigned idx0 = (unsigned)(nb * 128 + wn * 64 + l16);
#pragma unroll
        for (int fi = 0; fi < 4; ++fi) {
#pragma unroll
            for (int r = 0; r < 4; ++r) {
                const int ai = fi * 4 + r;
                float a0 = t2a[ai], b0 = t2b[ai];
#pragma unroll
                for (int fj = 0; fj < 4; ++fj) {
                    float v = acc[fi][fj][r];
                    float wv = __uint_as_float(
                        (__float_as_uint(v) & 0xFFFFE000u) | (idx0 + fj * 16));
                    float mn = fminf(a0, wv);
                    a0 = fmaxf(a0, wv);
                    b0 = fmaxf(b0, mn);
                }
                t2a[ai] = a0; t2b[ai] = b0;
            }
        }
        __syncthreads();   // staging for next tile complete
    }

    // epilogue: winners -> integer keys -> LDS -> per-(row,half) reduce
#pragma unroll
    for (int fi = 0; fi < 4; ++fi) {
#pragma unroll
        for (int r = 0; r < 4; ++r) {
            const int ai = fi * 4 + r;
            int row = wm * 64 + fi * 16 + quad * 4 + r;
            sm.e.ep[row][wn * 16 + l16] =
                make_uint2(pack_key(t2a[ai]), pack_key(t2b[ai]));
        }
    }
    __syncthreads();

    {
        int row = t >> 1, half = t & 1, h0 = half * 16;
        uint2 mv = sm.e.ep[row][h0];
#pragma unroll
        for (int i = 1; i < 16; ++i) {
            uint2 av = sm.e.ep[row][h0 + i];
            unsigned n0 = min(mv.x, av.x);
            unsigned n1 = min(max(mv.x, av.x), min(mv.y, av.y));
            mv.x = n0; mv.y = n1;
        }
        ((uint2*)keys)[(size_t)(g * 2 + half) * N_PIX + (mb * 128 + row)] = mv;
    }
}

// ---------------------------------------------------------------- kernel 3
// R3: 32 candidate-pairs per pixel (was 128). Stage 512 uint2/block,
// 2 scan passes; exact rescore unchanged.
__global__ __launch_bounds__(256) void final_kernel(
        const unsigned int* __restrict__ keys,
        const float* __restrict__ z, const float* __restrict__ emb,
        const float* __restrict__ zsq, const float* __restrict__ esq,
        float* __restrict__ out, float* __restrict__ idx_out,
        float* __restrict__ loss_out,
        double* __restrict__ lossAcc, unsigned* __restrict__ doneCnt) {
    __shared__ float ztile[16][260];
    __shared__ uint2 kt[16][33];
    __shared__ int sidx[16];
    int blk = blockIdx.x;                // 0..1023 = b*64 + hh
    int b = blk >> 6, hh = blk & 63;
    int t = threadIdx.x;
    int p0 = b * 1024 + hh * 16;
    const float* zb = z + (size_t)b * 262144 + hh * 16;
    {
        int px = t & 15, cb = t >> 4;
#pragma unroll
        for (int cc = 0; cc < 16; ++cc) {
            int c = cc * 16 + cb;
            ztile[px][c] = zb[(size_t)c * 1024 + px];
        }
    }
    {
        const uint2* kg = (const uint2*)keys;
#pragma unroll
        for (int itr = 0; itr < 2; ++itr) {
            int idx = itr * 256 + t;      // 0..511
            int px = idx & 15, hf = idx >> 4;   // hf 0..31
            kt[px][hf] = kg[(size_t)hf * N_PIX + p0 + px];
        }
    }
    __syncthreads();

    int wq = t >> 6, lane = t & 63;
#pragma unroll 1
    for (int i = 0; i < 4; ++i) {
        int px = wq * 4 + i;
        int p  = p0 + px;
        uint2 ka = (lane < 32) ? kt[px][lane] : make_uint2(~0u, ~0u);
        unsigned m = min(ka.x, ka.y);
#pragma unroll
        for (int off = 32; off >= 1; off >>= 1)
            m = min(m, (unsigned)__shfl_xor((int)m, off, 64));
        unsigned thr = (m >> 13) + 1600;   // margin 1600*2^-21 = 7.6e-4

        float4 zv = *(const float4*)&ztile[px][lane * 4];
        float zs = zsq[p];
        unsigned long long best = ~0ull;
#pragma unroll 1
        for (int pass = 0; pass < 2; ++pass) {
            unsigned kv = (pass == 0) ? ka.x : ka.y;
            unsigned long long mm = __ballot((kv >> 13) <= thr);
            while (mm) {
                int src = (int)__builtin_ctzll(mm);
                mm &= mm - 1;
                unsigned keyv = (unsigned)__shfl((int)kv, src, 64);
                int k = (int)(keyv & 0x1FFFu);
                const float4 ev = *(const float4*)(emb + (size_t)k * DDIM + lane * 4);
                double d = (double)zv.x * ev.x + (double)zv.y * ev.y
                         + (double)zv.z * ev.z + (double)zv.w * ev.w;
#pragma unroll
                for (int off = 32; off >= 1; off >>= 1)
                    d += __shfl_down(d, off, 64);
                d = __shfl(d, 0, 64);
                float df = (float)d;
                float s  = __fsub_rn(__fadd_rn(zs, esq[k]), __fmul_rn(2.0f, df));
                unsigned long long key =
                    ((unsigned long long)f32_sortable(s) << 32) | (unsigned)k;
                best = key < best ? key : best;
            }
        }
        if (lane == 0) {
            int k = (int)(unsigned)(best & 0xffffffffu);
            sidx[px] = k;
            idx_out[p] = (float)k;
        }
    }
    __syncthreads();

    int px2 = t & 15, cy = t >> 4;
    int kk = sidx[px2];
    const float* er = emb + (size_t)kk * DDIM;
    float* ob = out + (size_t)b * 262144 + hh * 16;
    float local = 0.f;
#pragma unroll 4
    for (int it = 0; it < 16; ++it) {
        int c = it * 16 + cy;
        float q = er[c];
        float d = q - ztile[px2][c];
        ob[(size_t)c * 1024 + px2] = q;
        local += d * d;
    }
#pragma unroll
    for (int off = 32; off >= 1; off >>= 1) local += __shfl_down(local, off, 64);
    __shared__ float wsum[4];
    if ((t & 63) == 0) wsum[t >> 6] = local;
    __syncthreads();
    if (t == 0) {
        double s = (double)wsum[0] + (double)wsum[1]
                 + (double)wsum[2] + (double)wsum[3];
        atomicAdd(lossAcc, s);
        __threadfence();
        unsigned old = atomicAdd(doneCnt, 1u);
        if (old == 1023u) {
            double tot = atomicAdd(lossAcc, 0.0);
            *loss_out = (float)(tot * (1.25 / 4194304.0));
        }
    }
}

// ----------------------------------------------------------------
extern "C" void kernel_launch(void* const* d_in, const int* in_sizes, int n_in,
                              void* d_out, int out_size, void* d_ws, size_t ws_size,
                              hipStream_t stream) {
    const float* z   = (const float*)d_in[0];
    const float* emb = (const float*)d_in[1];
    float* out = (float*)d_out;
    char* ws = (char*)d_ws;

    unsigned char* Af8 = (unsigned char*)(ws + WS_A8);
    unsigned char* Ef8 = (unsigned char*)(ws + WS_E8);
    unsigned int* keys = (unsigned int*)(ws + WS_KEYS);
    float* zsq      = (float*)(ws + WS_ZSQ);
    float* esq      = (float*)(ws + WS_ESQ);
    double* lossAcc = (double*)(ws + WS_LOSS);
    unsigned* doneCnt = (unsigned*)(ws + WS_CNT);

    prep_kernel<<<768, 256, 0, stream>>>(z, emb, Af8, Ef8, zsq, esq,
                                         lossAcc, doneCnt);
    mfma_score_kernel<<<dim3(16, 128), 256, 0, stream>>>(Af8, Ef8, keys);
    final_kernel<<<1024, 256, 0, stream>>>(keys, z, emb, zsq, esq,
                                           out, out + 4194305, out + 4194304,
                                           lossAcc, doneCnt);
}

// Round 5
// 189.138 us; speedup vs baseline: 1.1572x; 1.0461x over previous
//
#include <hip/hip_runtime.h>
#include <cstdint>
#include <cstddef>

#define N_PIX   16384
#define K_EMB   8192
#define DDIM    256

// ws layout (bytes)
#define WS_A8       0           // A fp8 chunk-major [128][8][4096]   4194304
#define WS_E8       4194304     // E fp8 (x8192) [64][8][4096]        2097152
#define WS_KEYS     6291456     // keys [32 subs][16384] uint2        4194304
#define WS_ZSQ      23068672    // 16384*4
#define WS_ESQ      23134208    // 8192*4
#define WS_LOSS     23166976    // 8
#define WS_CNT      23166984    // 4

typedef float f32x4 __attribute__((ext_vector_type(4)));

__device__ __forceinline__ unsigned int f32_sortable(float f) {
    unsigned int u = __float_as_uint(f);
    return (u & 0x80000000u) ? ~u : (u | 0x80000000u);
}

// fp32 -> OCP e4m3fn RNE (fallback path; handles subnormals)
__device__ __forceinline__ unsigned char f2fp8(float x) {
    unsigned ub = __float_as_uint(x);
    unsigned sgn = (ub >> 24) & 0x80u;
    unsigned b = ub & 0x7FFFFFFFu;
    unsigned out;
    if (__uint_as_float(b) < 0.015625f) {
        out = (unsigned)(int)rintf(__uint_as_float(b) * 512.0f);
    } else {
        unsigned r = b + 0x7FFFFu + ((b >> 20) & 1u);
        int er = (int)(r >> 23) - 127;
        out = (unsigned)(((er + 7) << 3) | ((r >> 20) & 7u));
    }
    return (unsigned char)(out | sgn);
}

#if defined(__has_builtin)
#if __has_builtin(__builtin_amdgcn_cvt_pk_fp8_f32)
#define HAVE_CVT_FP8 1
#endif
#endif

__device__ __forceinline__ unsigned pack4_fp8(float a, float b, float c, float d) {
#ifdef HAVE_CVT_FP8
    int pk = 0;
    pk = __builtin_amdgcn_cvt_pk_fp8_f32(a, b, pk, false);
    pk = __builtin_amdgcn_cvt_pk_fp8_f32(c, d, pk, true);
    return (unsigned)pk;
#else
    return (unsigned)f2fp8(a) | ((unsigned)f2fp8(b) << 8)
         | ((unsigned)f2fp8(c) << 16) | ((unsigned)f2fp8(d) << 24);
#endif
}

__device__ __forceinline__ void async16(const unsigned char* g, unsigned char* l) {
    __builtin_amdgcn_global_load_lds(
        (const __attribute__((address_space(1))) void*)g,
        (__attribute__((address_space(3))) void*)l, 16, 0, 0);
}

// np pairwise-sum of squares over 256 contiguous LDS floats (one thread)
// (kept bit-identical: zsq enters the f32 score s and must stay on the
//  same rounding grid that passed vs the f32 reference)
__device__ __forceinline__ float np_pairwise_sq256(const float* row) {
    float r[16];
#pragma unroll
    for (int j = 0; j < 16; ++j) r[j] = 0.f;
#pragma unroll
    for (int c = 0; c < 256; ++c) {
        float x  = row[c];
        float sq = __fmul_rn(x, x);
        int slot = ((c >> 7) << 3) | (c & 7);
        r[slot] = __fadd_rn(r[slot], sq);
    }
    float h0 = __fadd_rn(
        __fadd_rn(__fadd_rn(r[0], r[1]), __fadd_rn(r[2], r[3])),
        __fadd_rn(__fadd_rn(r[4], r[5]), __fadd_rn(r[6], r[7])));
    float h1 = __fadd_rn(
        __fadd_rn(__fadd_rn(r[8], r[9]), __fadd_rn(r[10], r[11])),
        __fadd_rn(__fadd_rn(r[12], r[13]), __fadd_rn(r[14], r[15])));
    return __fadd_rn(h0, h1);
}

// chunk-major byte offset for (row-in-128 r, byte-column c) within one
// 32 KB block: ks = c>>5, h = (c>>4)&1, s = h ^ ((r>>2)&1)
__device__ __forceinline__ size_t cm_addr(int r, int c) {
    int ks = c >> 5;
    int h  = (c >> 4) & 1;
    int s  = h ^ ((r >> 2) & 1);
    return (size_t)ks * 4096 + (size_t)r * 32 + s * 16 + (c & 15);
}

// ---------------------------------------------------------------- kernel 1
// R4: z-branch loads vectorized to float4 (same bytes, 4x fewer insts).
// zsq/esq np-pairwise kept bit-identical.
__global__ __launch_bounds__(256) void prep_kernel(
        const float* __restrict__ z, const float* __restrict__ emb,
        unsigned char* __restrict__ Af8, unsigned char* __restrict__ Ef8,
        float* __restrict__ zsq, float* __restrict__ esq,
        double* __restrict__ lossAcc, unsigned* __restrict__ doneCnt) {
    __shared__ float tile[32][257];
    int blk = blockIdx.x;
    int t   = threadIdx.x;
    if (blk < 512) {
        int b   = blk >> 5;
        int hw0 = (blk & 31) * 32;
        const float* zb = z + (size_t)b * 262144 + hw0;
        int c0  = t >> 3;        // 32 c-rows per iteration
        int px4 = t & 7;         // 8 float4 lanes cover 32 px
#pragma unroll
        for (int cc = 0; cc < 8; ++cc) {
            int c = cc * 32 + c0;
            float4 v = *(const float4*)&zb[(size_t)c * 1024 + px4 * 4];
            tile[px4 * 4 + 0][c] = v.x;
            tile[px4 * 4 + 1][c] = v.y;
            tile[px4 * 4 + 2][c] = v.z;
            tile[px4 * 4 + 3][c] = v.w;
        }
        __syncthreads();
        int p0 = b * 1024 + hw0;
        int wv = t >> 6, lane = t & 63;
#pragma unroll
        for (int iter = 0; iter < 8; ++iter) {
            int pl = iter * 4 + wv;
            unsigned pk = pack4_fp8(tile[pl][lane * 4 + 0], tile[pl][lane * 4 + 1],
                                    tile[pl][lane * 4 + 2], tile[pl][lane * 4 + 3]);
            int p  = p0 + pl;
            int mb = p >> 7, r = p & 127;
            *(unsigned*)(Af8 + (size_t)mb * 32768 + cm_addr(r, lane * 4)) = pk;
        }
        if (t < 32) zsq[p0 + t] = np_pairwise_sq256(tile[t]);
        if (blk == 0 && t == 0) { *lossAcc = 0.0; *doneCnt = 0u; }
    } else {
        int k0 = (blk - 512) * 32;
        const float4* eg = (const float4*)(emb + (size_t)k0 * DDIM);
#pragma unroll
        for (int i = 0; i < 8; ++i) {
            int idx = i * 256 + t;
            int row = idx >> 6, c4 = idx & 63;
            float4 v = eg[idx];
            *(float4*)&tile[row][c4 * 4] = v;
        }
        __syncthreads();
#pragma unroll
        for (int i = 0; i < 8; ++i) {
            int idx = i * 256 + t;
            int row = idx >> 6, c4 = idx & 63;
            const float* rp = &tile[row][c4 * 4];
            int kg = k0 + row;
            int nb = kg >> 7, rr = kg & 127;
            *(unsigned*)(Ef8 + (size_t)nb * 32768 + cm_addr(rr, c4 * 4)) =
                pack4_fp8(rp[0] * 8192.0f, rp[1] * 8192.0f,
                          rp[2] * 8192.0f, rp[3] * 8192.0f);
        }
        if (t < 32) esq[k0 + t] = np_pairwise_sq256(tile[t]);
    }
}

// winner float (idx in low 13 mantissa bits) -> integer key
__device__ __forceinline__ unsigned pack_key(float w) {
    float uf = __builtin_fmaf(w, -512.0f, 262144.0f);
    uf = fminf(uf, 524287.0f);
    unsigned u = (unsigned)uf;
    return (u << 13) | (__float_as_uint(w) & 0x1FFFu);
}

// ---------------------------------------------------------------- kernel 2
// unchanged from R3 (nb-sweep, float-domain top-2, 55-67 us)
__global__ __launch_bounds__(256) void mfma_score_kernel(
        const unsigned char* __restrict__ Af8,
        const unsigned char* __restrict__ Ef8,
        unsigned int* __restrict__ keys) {
    union SM {
        struct { unsigned char As[8][4096]; unsigned char Bs[8][4096]; } k; // 64 KB
        struct { uint2 ep[128][33]; } e;
    };
    __shared__ SM sm;

    const int g  = blockIdx.x;
    const int mb = blockIdx.y;
    const int t = threadIdx.x;
    const int w = t >> 6, lane = t & 63;
    const int wm = w >> 1, wn = w & 1;
    const int quad = lane >> 4, l16 = lane & 15;

    const unsigned char* Ag = Af8 + (size_t)mb * 32768 + t * 16;
#pragma unroll
    for (int ks = 0; ks < 8; ++ks)
        async16(Ag + ks * 4096, &sm.k.As[ks][t * 16]);
    {
        const unsigned char* Eg = Ef8 + (size_t)(g * 4) * 32768 + t * 16;
#pragma unroll
        for (int ks = 0; ks < 8; ++ks)
            async16(Eg + ks * 4096, &sm.k.Bs[ks][t * 16]);
    }

    int aaddr[4], baddr[4];
#pragma unroll
    for (int fi = 0; fi < 4; ++fi) {
        int row = wm * 64 + fi * 16 + l16;
        int gg  = (quad >> 1) ^ ((row >> 2) & 1);
        aaddr[fi] = row * 32 + gg * 16 + (quad & 1) * 8;
    }
#pragma unroll
    for (int fj = 0; fj < 4; ++fj) {
        int row = wn * 64 + fj * 16 + l16;
        int gg  = (quad >> 1) ^ ((row >> 2) & 1);
        baddr[fj] = row * 32 + gg * 16 + (quad & 1) * 8;
    }

    __syncthreads();

    long long afr[4][8];
#pragma unroll
    for (int fi = 0; fi < 4; ++fi)
#pragma unroll
        for (int ks = 0; ks < 8; ++ks)
            afr[fi][ks] = *(const long long*)&sm.k.As[ks][aaddr[fi]];

    const float NEGINF = __int_as_float(0xFF800000);
    float t2a[16], t2b[16];
#pragma unroll
    for (int i = 0; i < 16; ++i) { t2a[i] = NEGINF; t2b[i] = NEGINF; }

#pragma unroll 1
    for (int j = 0; j < 4; ++j) {
        f32x4 acc[4][4];
#pragma unroll
        for (int i = 0; i < 4; ++i)
#pragma unroll
            for (int jj = 0; jj < 4; ++jj)
#pragma unroll
                for (int r = 0; r < 4; ++r) acc[i][jj][r] = 0.f;

#pragma unroll
        for (int ks = 0; ks < 8; ++ks) {
            long long bfr[4];
#pragma unroll
            for (int fj = 0; fj < 4; ++fj)
                bfr[fj] = *(const long long*)&sm.k.Bs[ks][baddr[fj]];
            __builtin_amdgcn_s_setprio(1);
#pragma unroll
            for (int fi = 0; fi < 4; ++fi)
#pragma unroll
                for (int fj = 0; fj < 4; ++fj)
                    acc[fi][fj] = __builtin_amdgcn_mfma_f32_16x16x32_fp8_fp8(
                        afr[fi][ks], bfr[fj], acc[fi][fj], 0, 0, 0);
            __builtin_amdgcn_s_setprio(0);
        }
        __syncthreads();

        if (j < 3) {
            const unsigned char* Eg =
                Ef8 + (size_t)(g * 4 + j + 1) * 32768 + t * 16;
#pragma unroll
            for (int ks = 0; ks < 8; ++ks)
                async16(Eg + ks * 4096, &sm.k.Bs[ks][t * 16]);
        }

        const int nb = g * 4 + j;
        const unsigned idx0 = (unsigned)(nb * 128 + wn * 64 + l16);
#pragma unroll
        for (int fi = 0; fi < 4; ++fi) {
#pragma unroll
            for (int r = 0; r < 4; ++r) {
                const int ai = fi * 4 + r;
                float a0 = t2a[ai], b0 = t2b[ai];
#pragma unroll
                for (int fj = 0; fj < 4; ++fj) {
                    float v = acc[fi][fj][r];
                    float wv = __uint_as_float(
                        (__float_as_uint(v) & 0xFFFFE000u) | (idx0 + fj * 16));
                    float mn = fminf(a0, wv);
                    a0 = fmaxf(a0, wv);
                    b0 = fmaxf(b0, mn);
                }
                t2a[ai] = a0; t2b[ai] = b0;
            }
        }
        __syncthreads();
    }

#pragma unroll
    for (int fi = 0; fi < 4; ++fi) {
#pragma unroll
        for (int r = 0; r < 4; ++r) {
            const int ai = fi * 4 + r;
            int row = wm * 64 + fi * 16 + quad * 4 + r;
            sm.e.ep[row][wn * 16 + l16] =
                make_uint2(pack_key(t2a[ai]), pack_key(t2b[ai]));
        }
    }
    __syncthreads();

    {
        int row = t >> 1, half = t & 1, h0 = half * 16;
        uint2 mv = sm.e.ep[row][h0];
#pragma unroll
        for (int i = 1; i < 16; ++i) {
            uint2 av = sm.e.ep[row][h0 + i];
            unsigned n0 = min(mv.x, av.x);
            unsigned n1 = min(max(mv.x, av.x), min(mv.y, av.y));
            mv.x = n0; mv.y = n1;
        }
        ((uint2*)keys)[(size_t)(g * 2 + half) * N_PIX + (mb * 128 + row)] = mv;
    }
}

// ---------------------------------------------------------------- kernel 3
// R4 restructure: latency-bound serial rescore -> 3 phases:
//  A: per-pixel threshold + ballot-compaction of candidate k's into LDS
//  B: parallel rescore, one candidate per 16-lane group (16 concurrent
//     per block), coalesced 4x float4 emb row loads, double dot,
//     4-step group shfl reduce; f32 score arithmetic bit-identical.
//  C: per-pixel u64-key min reduction (16 threads/pixel).
__global__ __launch_bounds__(256) void final_kernel(
        const unsigned int* __restrict__ keys,
        const float* __restrict__ z, const float* __restrict__ emb,
        const float* __restrict__ zsq, const float* __restrict__ esq,
        float* __restrict__ out, float* __restrict__ idx_out,
        float* __restrict__ loss_out,
        double* __restrict__ lossAcc, unsigned* __restrict__ doneCnt) {
    __shared__ float ztile[16][260];
    __shared__ uint2 kt[16][33];
    __shared__ int   scand[16][64];
    __shared__ unsigned long long ckey[1024];
    __shared__ int   soff[17];
    __shared__ int   scnt[16];
    __shared__ int   pxmap[1024];
    __shared__ float szs[16];
    __shared__ int   sidx[16];

    int blk = blockIdx.x;                // 0..1023 = b*64 + hh
    int b = blk >> 6, hh = blk & 63;
    int t = threadIdx.x;
    int p0 = b * 1024 + hh * 16;
    const float* zb = z + (size_t)b * 262144 + hh * 16;
    {
        int px = t & 15, cb = t >> 4;
#pragma unroll
        for (int cc = 0; cc < 16; ++cc) {
            int c = cc * 16 + cb;
            ztile[px][c] = zb[(size_t)c * 1024 + px];
        }
    }
    {
        const uint2* kg = (const uint2*)keys;
#pragma unroll
        for (int itr = 0; itr < 2; ++itr) {
            int idx = itr * 256 + t;      // 0..511
            int px = idx & 15, hf = idx >> 4;
            kt[px][hf] = kg[(size_t)hf * N_PIX + p0 + px];
        }
    }
    if (t < 16) szs[t] = zsq[p0 + t];
    __syncthreads();

    // ---- Phase A: threshold + compact candidate lists
    {
        int wq = t >> 6, lane = t & 63;
#pragma unroll 1
        for (int i = 0; i < 4; ++i) {
            int px = wq * 4 + i;
            uint2 ka = (lane < 32) ? kt[px][lane] : make_uint2(~0u, ~0u);
            unsigned m = min(ka.x, ka.y);
#pragma unroll
            for (int off = 32; off >= 1; off >>= 1)
                m = min(m, (unsigned)__shfl_xor((int)m, off, 64));
            unsigned thr = (m >> 13) + 1600;   // margin 1600*2^-21 = 7.6e-4

            bool h0 = (lane < 32) && ((ka.x >> 13) <= thr);
            bool h1 = (lane < 32) && ((ka.y >> 13) <= thr);
            unsigned long long m0 = __ballot(h0);
            unsigned long long m1 = __ballot(h1);
            int c0 = __popcll(m0);
            unsigned long long below = (lane == 63) ? ~0ull >> 1
                                     : ((1ull << lane) - 1);
            if (h0) scand[px][__popcll(m0 & below)] = (int)(ka.x & 0x1FFFu);
            if (h1) scand[px][c0 + __popcll(m1 & below)] = (int)(ka.y & 0x1FFFu);
            if (lane == 0) scnt[px] = c0 + __popcll(m1);
        }
    }
    __syncthreads();

    // ---- scan counts -> soff (wave 0), then pxmap
    if (t < 64) {
        int v = (t < 16) ? scnt[t] : 0;
#pragma unroll
        for (int o = 1; o < 16; o <<= 1) {
            int u = __shfl_up(v, o, 64);
            if (t >= o) v += u;
        }
        if (t < 16) soff[t + 1] = v;
        if (t == 0) soff[0] = 0;
    }
    __syncthreads();
    int total = soff[16];
    for (int f = t; f < total; f += 256) {
        int lo = 0, hi = 15;
        while (lo < hi) {
            int mid = (lo + hi + 1) >> 1;
            if (soff[mid] <= f) lo = mid; else hi = mid - 1;
        }
        pxmap[f] = lo;
    }
    __syncthreads();

    // ---- Phase B: parallel rescore, one candidate per 16-lane group
    {
        int gid = t >> 4, l16 = t & 15;
        const float4* emb4 = (const float4*)emb;
#pragma unroll 1
        for (int f = gid; f < total; f += 16) {
            int px = pxmap[f];
            int k  = scand[px][f - soff[px]];
            double d = 0.0;
#pragma unroll
            for (int q = 0; q < 4; ++q) {
                float4 ev = emb4[(size_t)k * 64 + q * 16 + l16];
                const float* zp = &ztile[px][(q * 16 + l16) * 4];
                d += (double)zp[0] * ev.x + (double)zp[1] * ev.y
                   + (double)zp[2] * ev.z + (double)zp[3] * ev.w;
            }
#pragma unroll
            for (int o = 1; o < 16; o <<= 1) d += __shfl_xor(d, o, 64);
            if (l16 == 0) {
                float df = (float)d;
                float s  = __fsub_rn(__fadd_rn(szs[px], esq[k]),
                                     __fmul_rn(2.0f, df));
                ckey[f] = ((unsigned long long)f32_sortable(s) << 32)
                        | (unsigned)k;
            }
        }
    }
    __syncthreads();

    // ---- Phase C: per-pixel u64 min (16 threads each)
    {
        int cpx = t >> 4, ci = t & 15;
        unsigned long long best = ~0ull;
        for (int f = soff[cpx] + ci; f < soff[cpx + 1]; f += 16) {
            unsigned long long v = ckey[f];
            best = v < best ? v : best;
        }
#pragma unroll
        for (int o = 1; o < 16; o <<= 1) {
            unsigned long long ov =
                (unsigned long long)__shfl_xor((long long)best, o, 64);
            best = ov < best ? ov : best;
        }
        if (ci == 0) {
            int k = (int)(unsigned)(best & 0xffffffffu);
            sidx[cpx] = k;
            idx_out[p0 + cpx] = (float)k;
        }
    }
    __syncthreads();

    // ---- gather + loss (unchanged)
    int px2 = t & 15, cy = t >> 4;
    int kk = sidx[px2];
    const float* er = emb + (size_t)kk * DDIM;
    float* ob = out + (size_t)b * 262144 + hh * 16;
    float local = 0.f;
#pragma unroll 4
    for (int it = 0; it < 16; ++it) {
        int c = it * 16 + cy;
        float q = er[c];
        float d = q - ztile[px2][c];
        ob[(size_t)c * 1024 + px2] = q;
        local += d * d;
    }
#pragma unroll
    for (int off = 32; off >= 1; off >>= 1) local += __shfl_down(local, off, 64);
    __shared__ float wsum[4];
    if ((t & 63) == 0) wsum[t >> 6] = local;
    __syncthreads();
    if (t == 0) {
        double s = (double)wsum[0] + (double)wsum[1]
                 + (double)wsum[2] + (double)wsum[3];
        atomicAdd(lossAcc, s);
        __threadfence();
        unsigned old = atomicAdd(doneCnt, 1u);
        if (old == 1023u) {
            double tot = atomicAdd(lossAcc, 0.0);
            *loss_out = (float)(tot * (1.25 / 4194304.0));
        }
    }
}

// ----------------------------------------------------------------
extern "C" void kernel_launch(void* const* d_in, const int* in_sizes, int n_in,
                              void* d_out, int out_size, void* d_ws, size_t ws_size,
                              hipStream_t stream) {
    const float* z   = (const float*)d_in[0];
    const float* emb = (const float*)d_in[1];
    float* out = (float*)d_out;
    char* ws = (char*)d_ws;

    unsigned char* Af8 = (unsigned char*)(ws + WS_A8);
    unsigned char* Ef8 = (unsigned char*)(ws + WS_E8);
    unsigned int* keys = (unsigned int*)(ws + WS_KEYS);
    float* zsq      = (float*)(ws + WS_ZSQ);
    float* esq      = (float*)(ws + WS_ESQ);
    double* lossAcc = (double*)(ws + WS_LOSS);
    unsigned* doneCnt = (unsigned*)(ws + WS_CNT);

    prep_kernel<<<768, 256, 0, stream>>>(z, emb, Af8, Ef8, zsq, esq,
                                         lossAcc, doneCnt);
    mfma_score_kernel<<<dim3(16, 128), 256, 0, stream>>>(Af8, Ef8, keys);
    final_kernel<<<1024, 256, 0, stream>>>(keys, z, emb, zsq, esq,
                                           out, out + 4194305, out + 4194304,
                                           lossAcc, doneCnt);
}